// Round 1
// baseline (5714.627 us; speedup 1.0000x reference)
//
#include <hip/hip_runtime.h>
#include <hip/hip_bf16.h>
#include <math.h>

// Problem dims
#define C_DIM 256
#define H_DIM 180
#define W_DIM 360
#define L_DIM 180
#define M_DIM 181
#define HW 64800          // H*W
#define CH 46080          // C*H
#define NLAYERS 2

__device__ __forceinline__ float gelu_f(float x){
    return 0.5f * x * (1.0f + erff(x * 0.70710678118654752440f));
}

// -------------------- generic strided GEMM --------------------
// out[i][j] = sum_k A[i*a_is + k*a_ks] * B[k*b_ks + j*b_js]
// natural store: C[i*ldc + j]; TRANS store: C[j*ldc + i]
// EPI: 0 = store, 1 = gelu(acc), 2 = acc + C_old, 3 = gelu(acc + C_old)
// CPLX: A2 = A + a2off (imag), B2 = B + b2off, C2 = C + c2off
//   accR = a1*b1 - a2*b2 ; accI = a1*b2 + a2*b1
struct GemmP {
    const float* A; const float* B; float* C;
    int I, J, K;
    int a_is, a_ks, b_ks, b_js, ldc;
    long long aBS, bBS, cBS;     // batch strides (elements), batch = blockIdx.z
    int a2off, b2off, c2off;
};

template<bool TRANS, int EPI, bool CPLX>
__global__ __launch_bounds__(256) void gemm_k(GemmP p){
    __shared__ __align__(16) float As[CPLX ? 2 : 1][16][64];
    __shared__ __align__(16) float Bs[CPLX ? 2 : 1][16][64];

    const int tid = threadIdx.x;
    const int bj = blockIdx.x, bi = blockIdx.y, bz = blockIdx.z;
    const float* A = p.A + (long long)bz * p.aBS;
    const float* B = p.B + (long long)bz * p.bBS;
    float*       C = p.C + (long long)bz * p.cBS;

    float accR[4][4];
    float accI[4][4];
    #pragma unroll
    for (int a=0;a<4;a++)
        #pragma unroll
        for (int b=0;b<4;b++){ accR[a][b]=0.f; accI[a][b]=0.f; }

    const int ti = tid >> 4, tj = tid & 15;

    for (int k0 = 0; k0 < p.K; k0 += 16){
        // ---- load A tile [16k][64i] ----
        if (p.a_ks == 1){
            int r = tid >> 2, c0 = (tid & 3) * 4;
            int gi = bi*64 + r;
            #pragma unroll
            for (int u=0;u<4;u++){
                int gk = k0 + c0 + u;
                bool ok = (gi < p.I) && (gk < p.K);
                long long o = (long long)gi * p.a_is + gk;
                As[0][c0+u][r] = ok ? A[o] : 0.f;
                if (CPLX) As[1][c0+u][r] = ok ? A[o + p.a2off] : 0.f;
            }
        } else {
            int c = tid >> 4, r0 = (tid & 15) * 4;
            int gk = k0 + c;
            #pragma unroll
            for (int u=0;u<4;u++){
                int gi = bi*64 + r0 + u;
                bool ok = (gi < p.I) && (gk < p.K);
                long long o = (long long)gi * p.a_is + (long long)gk * p.a_ks;
                As[0][c][r0+u] = ok ? A[o] : 0.f;
                if (CPLX) As[1][c][r0+u] = ok ? A[o + p.a2off] : 0.f;
            }
        }
        // ---- load B tile [16k][64j] ----
        if (p.b_js == 1){
            int c = tid >> 4, j0 = (tid & 15) * 4;
            int gk = k0 + c;
            #pragma unroll
            for (int u=0;u<4;u++){
                int gj = bj*64 + j0 + u;
                bool ok = (gj < p.J) && (gk < p.K);
                long long o = (long long)gk * p.b_ks + gj;
                Bs[0][c][j0+u] = ok ? B[o] : 0.f;
                if (CPLX) Bs[1][c][j0+u] = ok ? B[o + p.b2off] : 0.f;
            }
        } else {
            int jr = tid >> 2, c0 = (tid & 3) * 4;
            int gj = bj*64 + jr;
            #pragma unroll
            for (int u=0;u<4;u++){
                int gk = k0 + c0 + u;
                bool ok = (gj < p.J) && (gk < p.K);
                long long o = (long long)gj * p.b_js + gk;
                Bs[0][c0+u][jr] = ok ? B[o] : 0.f;
                if (CPLX) Bs[1][c0+u][jr] = ok ? B[o + p.b2off] : 0.f;
            }
        }
        __syncthreads();

        #pragma unroll
        for (int k=0;k<16;k++){
            const float4 a1 = *reinterpret_cast<const float4*>(&As[0][k][ti*4]);
            const float4 b1 = *reinterpret_cast<const float4*>(&Bs[0][k][tj*4]);
            float a1v[4] = {a1.x,a1.y,a1.z,a1.w};
            float b1v[4] = {b1.x,b1.y,b1.z,b1.w};
            if (CPLX){
                const float4 a2 = *reinterpret_cast<const float4*>(&As[1][k][ti*4]);
                const float4 b2 = *reinterpret_cast<const float4*>(&Bs[1][k][tj*4]);
                float a2v[4] = {a2.x,a2.y,a2.z,a2.w};
                float b2v[4] = {b2.x,b2.y,b2.z,b2.w};
                #pragma unroll
                for (int ii=0;ii<4;ii++)
                    #pragma unroll
                    for (int jj=0;jj<4;jj++){
                        accR[ii][jj] += a1v[ii]*b1v[jj] - a2v[ii]*b2v[jj];
                        accI[ii][jj] += a1v[ii]*b2v[jj] + a2v[ii]*b1v[jj];
                    }
            } else {
                #pragma unroll
                for (int ii=0;ii<4;ii++)
                    #pragma unroll
                    for (int jj=0;jj<4;jj++)
                        accR[ii][jj] += a1v[ii]*b1v[jj];
            }
        }
        __syncthreads();
    }

    // ---- epilogue ----
    #pragma unroll
    for (int ii=0;ii<4;ii++){
        int i = bi*64 + ti*4 + ii;
        if (i >= p.I) continue;
        #pragma unroll
        for (int jj=0;jj<4;jj++){
            int j = bj*64 + tj*4 + jj;
            if (j >= p.J) continue;
            long long addr = TRANS ? (long long)j * p.ldc + i
                                   : (long long)i * p.ldc + j;
            float v = accR[ii][jj];
            if (EPI & 2) v += C[addr];
            if (EPI & 1) v = gelu_f(v);
            C[addr] = v;
            if (CPLX) C[addr + p.c2off] = accI[ii][jj];
        }
    }
}

// -------------------- twiddle tables --------------------
// fwdTw [360][362]: cols 0..180 = cos(2pi w m/360), cols 181..361 = -sin(...)
// invTw [362][360]: row 2m+s: s=0: sc*cos(2pi m w/360), s=1: -sc*sin(...)
//   sc = 1/360 for m in {0,180}, else 2/360
__global__ __launch_bounds__(256) void build_tw(float* fwdTw, float* invTw){
    int id = blockIdx.x * 256 + threadIdx.x;
    if (id < 360*362){
        int w = id / 362, j = id % 362;
        int m = (j < 181) ? j : (j - 181);
        int t = (w * m) % 360;
        float ang = 6.28318530717958647692f * (float)t / 360.0f;
        float s, c; sincosf(ang, &s, &c);
        fwdTw[id] = (j < 181) ? c : -s;
    }
    if (id < 362*360){
        int k = id / 360, w = id % 360;
        int m = k >> 1, s = k & 1;
        int t = (w * m) % 360;
        float ang = 6.28318530717958647692f * (float)t / 360.0f;
        float sn, cs; sincosf(ang, &sn, &cs);
        float sc = (m == 0 || m == 180) ? (1.0f/360.0f) : (2.0f/360.0f);
        invTw[id] = (s == 0) ? sc*cs : -sc*sn;
    }
}

// -------------------- w_spec permute --------------------
// w_spec [layer][ci][o][l][s] -> wtr [layer][l][s][o][ci]
__global__ __launch_bounds__(256) void build_wtr(const float* wspec, float* wtr){
    __shared__ float t[32][33];
    int zo = blockIdx.z;                 // layer*256 + o
    int layer = zo >> 8, o = zo & 255;
    int ls0 = blockIdx.x * 32, ci0 = blockIdx.y * 32;
    int tx = threadIdx.x, ty = threadIdx.y;   // 32 x 8
    #pragma unroll
    for (int r=0;r<4;r++){
        int ci = ci0 + ty + 8*r, ls = ls0 + tx;
        if (ls < 360)
            t[ty+8*r][tx] = wspec[(((long long)layer*256 + ci)*256 + o)*360 + ls];
    }
    __syncthreads();
    #pragma unroll
    for (int r=0;r<4;r++){
        int ls = ls0 + ty + 8*r, ci = ci0 + tx;
        if (ls < 360){
            int l = ls >> 1, s = ls & 1;
            wtr[(((long long)layer*180 + l)*2 + s)*65536 + o*256 + ci] = t[tx][ty+8*r];
        }
    }
}

// -------------------- spectral permute --------------------
// X [180][512][181] -> Y [181][512][180] : Y[m][b][l] = X[l][b][m]
__global__ __launch_bounds__(256) void permute_lm(const float* X, float* Y){
    __shared__ float t[32][33];
    int b = blockIdx.z;
    int m0 = blockIdx.x * 32, l0 = blockIdx.y * 32;
    int tx = threadIdx.x, ty = threadIdx.y;   // 32 x 8
    #pragma unroll
    for (int r=0;r<4;r++){
        int l = l0 + ty + 8*r, m = m0 + tx;
        if (l < 180 && m < 181)
            t[ty+8*r][tx] = X[(long long)l*92672 + b*181 + m];
    }
    __syncthreads();
    #pragma unroll
    for (int r=0;r<4;r++){
        int m = m0 + ty + 8*r, l = l0 + tx;
        if (m < 181 && l < 180)
            Y[(long long)m*92160 + b*180 + l] = t[tx][ty+8*r];
    }
}

extern "C" void kernel_launch(void* const* d_in, const int* in_sizes, int n_in,
                              void* d_out, int out_size, void* d_ws, size_t ws_size,
                              hipStream_t stream){
    const float* x      = (const float*)d_in[0];
    const float* pct    = (const float*)d_in[1];
    const float* pctinv = (const float*)d_in[2];
    const float* wspec  = (const float*)d_in[3];
    const float* winner = (const float*)d_in[4];
    const float* wfc1   = (const float*)d_in[5];
    const float* wfc2   = (const float*)d_in[6];
    const float* wout   = (const float*)d_in[7];
    float* outp = (float*)d_out;
    float* ws   = (float*)d_ws;

    // workspace layout (floats), with aliasing (lifetimes verified):
    float* wtr     = ws;                       // 47,185,920  [layer][l][s=re/im][o][ci]
    float* fwdTw   = wtr    + 47185920;        //    130,320
    float* invTw   = fwdTw  + 130320;          //    130,320
    float* xfBuf   = invTw  + 130320;          // 16,680,960  [m][s*256+c][h]  (also c3 / bufH lo)
    float* specBuf = xfBuf  + 16680960;        // 16,680,960  [m][l][512] / invLeg out (bufH hi)
    float* bufH    = xfBuf;                    // 33,177,600 spans xfBuf+specBuf
    float* c2Buf   = specBuf + 16680960;       // 16,680,960  [l][512][181]  (also bufY)
    float* bufY    = c2Buf;
    float* bufX    = c2Buf  + 16680960;        // 16,588,800  current activation [C][H][W]
    // total = 114,078,240 floats = 456.3 MB

    hipMemcpyAsync(bufX, x, (size_t)CH * W_DIM * sizeof(float),
                   hipMemcpyDeviceToDevice, stream);
    build_tw<<<510, 256, 0, stream>>>(fwdTw, invTw);
    build_wtr<<<dim3(12,8,512), dim3(32,8), 0, stream>>>(wspec, wtr);

    for (int layer = 0; layer < NLAYERS; layer++){
        GemmP p;
        // ---- forward DFT (real part): [CH x 360] * [360 x 181] -> xfBuf[m][0..255c][h]
        p.A = bufX; p.B = fwdTw; p.C = xfBuf;
        p.I = CH; p.J = 181; p.K = 360;
        p.a_is = 360; p.a_ks = 1; p.b_ks = 362; p.b_js = 1; p.ldc = 92160;
        p.aBS = 0; p.bBS = 0; p.cBS = 0; p.a2off = 0; p.b2off = 0; p.c2off = 0;
        gemm_k<true,0,false><<<dim3(3,720,1), 256, 0, stream>>>(p);
        // ---- forward DFT (imag part)
        p.B = fwdTw + 181; p.C = xfBuf + CH;
        gemm_k<true,0,false><<<dim3(3,720,1), 256, 0, stream>>>(p);

        // ---- forward Legendre, batched over m: [512 x 180] * pct[m]^T -> specBuf[m][l][512]
        p.A = xfBuf; p.B = pct; p.C = specBuf;
        p.I = 512; p.J = 180; p.K = 180;
        p.a_is = 180; p.a_ks = 1; p.b_ks = 1; p.b_js = 180; p.ldc = 512;
        p.aBS = 92160; p.bBS = 32400; p.cBS = 92160;
        p.a2off = 0; p.b2off = 0; p.c2off = 0;
        gemm_k<true,0,false><<<dim3(3,8,181), 256, 0, stream>>>(p);

        // ---- dhconv, batched over l (complex): wtr[l] (256x256 re/im) * spec -> c2Buf[l][512][181]
        p.A = wtr + (long long)layer * 180 * 131072; p.B = specBuf; p.C = c2Buf;
        p.I = 256; p.J = 181; p.K = 256;
        p.a_is = 256; p.a_ks = 1; p.b_ks = 1; p.b_js = 92160; p.ldc = 181;
        p.aBS = 131072; p.bBS = 512; p.cBS = 92672;
        p.a2off = 65536; p.b2off = 256; p.c2off = 46336;
        gemm_k<false,0,true><<<dim3(3,4,180), 256, 0, stream>>>(p);

        // ---- permute [l][512][m] -> [m][512][l]
        permute_lm<<<dim3(6,6,512), dim3(32,8), 0, stream>>>(c2Buf, xfBuf);

        // ---- inverse Legendre, batched over m: [512 x 180] * pct_inv[m] -> specBuf[m][512][h]
        p.A = xfBuf; p.B = pctinv; p.C = specBuf;
        p.I = 512; p.J = 180; p.K = 180;
        p.a_is = 180; p.a_ks = 1; p.b_ks = 180; p.b_js = 1; p.ldc = 180;
        p.aBS = 92160; p.bBS = 32400; p.cBS = 92160;
        p.a2off = 0; p.b2off = 0; p.c2off = 0;
        gemm_k<false,0,false><<<dim3(3,8,181), 256, 0, stream>>>(p);

        // ---- inverse DFT: A k-major [CH x 362] * invTw [362 x 360] -> bufY [CH][W]
        p.A = specBuf; p.B = invTw; p.C = bufY;
        p.I = CH; p.J = 360; p.K = 362;
        p.a_is = 1; p.a_ks = CH; p.b_ks = 360; p.b_js = 1; p.ldc = 360;
        p.aBS = 0; p.bBS = 0; p.cBS = 0;
        gemm_k<false,0,false><<<dim3(6,720,1), 256, 0, stream>>>(p);

        // ---- inner skip conv + add isht + gelu: bufY = gelu(winner@bufX + bufY)
        p.A = winner + (long long)layer * 65536; p.B = bufX; p.C = bufY;
        p.I = 256; p.J = HW; p.K = 256;
        p.a_is = 256; p.a_ks = 1; p.b_ks = HW; p.b_js = 1; p.ldc = HW;
        gemm_k<false,3,false><<<dim3(1013,4,1), 256, 0, stream>>>(p);

        // ---- fc1 + gelu: bufH = gelu(wfc1@bufY)
        p.A = wfc1 + (long long)layer * 131072; p.B = bufY; p.C = bufH;
        p.I = 512; p.J = HW; p.K = 256;
        p.a_is = 256; p.a_ks = 1; p.b_ks = HW; p.b_js = 1; p.ldc = HW;
        gemm_k<false,1,false><<<dim3(1013,8,1), 256, 0, stream>>>(p);

        // ---- fc2 + residual + inter-block gelu: bufX = gelu(wfc2@bufH + bufX)
        p.A = wfc2 + (long long)layer * 131072; p.B = bufH; p.C = bufX;
        p.I = 256; p.J = HW; p.K = 512;
        p.a_is = 512; p.a_ks = 1; p.b_ks = HW; p.b_js = 1; p.ldc = HW;
        gemm_k<false,3,false><<<dim3(1013,4,1), 256, 0, stream>>>(p);
    }

    // ---- final output conv: d_out = wout @ bufX  [128 x HW]
    GemmP p;
    p.A = wout; p.B = bufX; p.C = outp;
    p.I = 128; p.J = HW; p.K = 256;
    p.a_is = 256; p.a_ks = 1; p.b_ks = HW; p.b_js = 1; p.ldc = HW;
    p.aBS = 0; p.bBS = 0; p.cBS = 0; p.a2off = 0; p.b2off = 0; p.c2off = 0;
    gemm_k<false,0,false><<<dim3(1013,2,1), 256, 0, stream>>>(p);
}

// Round 2
// 1518.766 us; speedup vs baseline: 3.7627x; 3.7627x over previous
//
#include <hip/hip_runtime.h>
#include <hip/hip_bf16.h>
#include <math.h>

typedef _Float16 half8 __attribute__((ext_vector_type(8)));
typedef _Float16 half4v __attribute__((ext_vector_type(4)));
typedef float floatx4 __attribute__((ext_vector_type(4)));

__device__ __forceinline__ float gelu_f(float x){
    return 0.5f * x * (1.0f + erff(x * 0.70710678118654752440f));
}

// guarded 16B (8 x f16) load; kleft = K - gk (may be <=0)
__device__ __forceinline__ uint4 ldg16(const _Float16* p, bool rowok, int kleft){
    if (rowok && kleft >= 8) return *(const uint4*)p;
    union { uint4 u; _Float16 h[8]; } z;
    z.u = make_uint4(0u,0u,0u,0u);
    if (rowok){
        int n = kleft < 8 ? kleft : 8;
        for (int e=0;e<n;e++) z.h[e] = p[e];
    }
    return z.u;
}

// ---------------- generic f16 MFMA GEMM ----------------
// C[i][j] = sum_k A[i][k] * Bt[j][k]
// SM: 0 = row store (addr=i*ldc+j), 1 = trans store (addr=j*ldc+i, needs I%16==0)
// EPI: 0 none, 1 gelu, 3 add-old-C + gelu
struct GemmP {
    const _Float16* A; const _Float16* Bt; void* C;
    long long aBS, bBS, cBS;
    int lda, ldb, ldc;
    int I, J, K;
};

template<int SM, int EPI, typename CT>
__global__ __launch_bounds__(256, 2) void mfma_gemm(GemmP p){
    __shared__ _Float16 As[128][40];
    __shared__ _Float16 Bs[128][40];
    const int tid  = threadIdx.x;
    const int lane = tid & 63, wave = tid >> 6;
    const int wr = wave >> 1, wc = wave & 1;
    const int bj = blockIdx.x, bi = blockIdx.y, bz = blockIdx.z;
    const _Float16* A  = p.A  + (long long)bz * p.aBS;
    const _Float16* Bt = p.Bt + (long long)bz * p.bBS;
    CT* C = (CT*)p.C + (long long)bz * p.cBS;

    floatx4 acc[4][4];
    #pragma unroll
    for (int a=0;a<4;a++)
        #pragma unroll
        for (int b=0;b<4;b++) acc[a][b] = (floatx4){0.f,0.f,0.f,0.f};

    const int r0 = tid >> 2;       // 0..63
    const int ch = tid & 3;        // 16B chunk within 32-k tile
    const int la = lane & 15, lb = lane >> 4;

    for (int k0 = 0; k0 < p.K; k0 += 32){
        const int kleft = p.K - (k0 + ch*8);
        #pragma unroll
        for (int it=0; it<2; it++){
            int r = r0 + it*64;
            int gi = bi*128 + r;
            uint4 v = ldg16(A + (long long)gi*p.lda + k0 + ch*8, gi < p.I, kleft);
            *(uint4*)&As[r][ch*8] = v;
        }
        #pragma unroll
        for (int it=0; it<2; it++){
            int r = r0 + it*64;
            int gj = bj*128 + r;
            uint4 v = ldg16(Bt + (long long)gj*p.ldb + k0 + ch*8, gj < p.J, kleft);
            *(uint4*)&Bs[r][ch*8] = v;
        }
        __syncthreads();

        half8 af[4], bf[4];
        #pragma unroll
        for (int f=0; f<4; f++) af[f] = *(const half8*)&As[wr*64 + f*16 + la][lb*8];
        #pragma unroll
        for (int f=0; f<4; f++) bf[f] = *(const half8*)&Bs[wc*64 + f*16 + la][lb*8];
        #pragma unroll
        for (int mi=0; mi<4; mi++)
            #pragma unroll
            for (int nj=0; nj<4; nj++)
                acc[mi][nj] = __builtin_amdgcn_mfma_f32_16x16x32_f16(
                    af[mi], bf[nj], acc[mi][nj], 0, 0, 0);
        __syncthreads();
    }

    // epilogue. C/D layout: col = lane&15, row = (lane>>4)*4 + reg
    #pragma unroll
    for (int mi=0; mi<4; mi++){
        int ibase = bi*128 + wr*64 + mi*16 + lb*4;
        #pragma unroll
        for (int nj=0; nj<4; nj++){
            int j = bj*128 + wc*64 + nj*16 + la;
            if (j >= p.J) continue;
            if (SM == 0){
                #pragma unroll
                for (int r=0;r<4;r++){
                    int i = ibase + r;
                    if (i >= p.I) continue;
                    float v = acc[mi][nj][r];
                    long long addr = (long long)i*p.ldc + j;
                    if (EPI & 2) v += (float)C[addr];
                    if (EPI & 1) v = gelu_f(v);
                    C[addr] = (CT)v;
                }
            } else {
                CT* cp = C + (long long)j*p.ldc + ibase;
                float v[4];
                #pragma unroll
                for (int r=0;r<4;r++) v[r] = acc[mi][nj][r];
                if (EPI & 2){
                    half4v old = *(const half4v*)(const void*)cp;
                    #pragma unroll
                    for (int r=0;r<4;r++) v[r] += (float)old[r];
                }
                if (EPI & 1){
                    #pragma unroll
                    for (int r=0;r<4;r++) v[r] = gelu_f(v[r]);
                }
                half4v outv;
                #pragma unroll
                for (int r=0;r<4;r++) outv[r] = (_Float16)v[r];
                *(half4v*)(void*)cp = outv;
            }
        }
    }
}

// ---------------- transpose / cast helpers ----------------
// in [R][Cc] -> out [Cc][R] (f16 out)
template<typename TI>
__global__ __launch_bounds__(256) void transpose_k(const TI* in, _Float16* out, int R, int Cc){
    __shared__ float t[32][33];
    int c0 = blockIdx.x*32, r0 = blockIdx.y*32;
    int tx = threadIdx.x & 31, ty = threadIdx.x >> 5;
    #pragma unroll
    for (int q=0;q<4;q++){
        int r = r0 + ty + 8*q, c = c0 + tx;
        if (r < R && c < Cc) t[ty+8*q][tx] = (float)in[(long long)r*Cc + c];
    }
    __syncthreads();
    #pragma unroll
    for (int q=0;q<4;q++){
        int c = c0 + ty + 8*q, r = r0 + tx;
        if (c < Cc && r < R) out[(long long)c*R + r] = (_Float16)t[tx][ty+8*q];
    }
}

__global__ __launch_bounds__(256) void cast_k(const float* in, _Float16* out, int n){
    int i = blockIdx.x*256 + threadIdx.x;
    if (i < n) out[i] = (_Float16)in[i];
}

// pct [m][l][h] f32 -> pct16 [m][l][192]
__global__ __launch_bounds__(256) void cvt_pct_k(const float* in, _Float16* out){
    int id = blockIdx.x*256 + threadIdx.x;
    if (id >= 181*180*180) return;
    int m = id / 32400, r = id % 32400;
    int l = r / 180, h = r % 180;
    out[(long long)m*34560 + l*192 + h] = (_Float16)in[id];
}

// pctinv [m][l][h] -> pctinvT [m][h][192(l)]
__global__ __launch_bounds__(256) void cvt_pctinvT_k(const float* in, _Float16* out){
    __shared__ float t[32][33];
    int m = blockIdx.z;
    int h0 = blockIdx.x*32, l0 = blockIdx.y*32;
    int tx = threadIdx.x & 31, ty = threadIdx.x >> 5;
    #pragma unroll
    for (int q=0;q<4;q++){
        int l = l0+ty+8*q, h = h0+tx;
        if (l<180 && h<180) t[ty+8*q][tx] = in[(long long)m*32400 + l*180 + h];
    }
    __syncthreads();
    #pragma unroll
    for (int q=0;q<4;q++){
        int h = h0+ty+8*q, l = l0+tx;
        if (h<180 && l<180) out[(long long)m*34560 + h*192 + l] = (_Float16)t[tx][ty+8*q];
    }
}

// twiddles: fwdTwT [362][360], invTwT [360][368]
__global__ __launch_bounds__(256) void build_tw16_k(_Float16* fwdTwT, _Float16* invTwT){
    int id = blockIdx.x*256 + threadIdx.x;
    if (id < 362*360){
        int j = id / 360, w = id % 360;
        int m = (j < 181) ? j : j - 181;
        int t = (w*m) % 360;
        float ang = 6.28318530717958647692f * (float)t / 360.f;
        fwdTwT[id] = (_Float16)((j < 181) ? cosf(ang) : -sinf(ang));
    }
    if (id < 360*368){
        int w = id / 368, k = id % 368;
        if (k < 362){
            int m = (k < 181) ? k : k - 181;
            int t = (w*m) % 360;
            float ang = 6.28318530717958647692f * (float)t / 360.f;
            float sc = (m==0 || m==180) ? (1.f/360.f) : (2.f/360.f);
            invTwT[w*368 + k] = (_Float16)((k < 181) ? sc*cosf(ang) : -sc*sinf(ang));
        } else invTwT[w*368 + k] = (_Float16)0.f;
    }
}

// wspec [layer][ci][o][l][s] -> Wx [layer][l][512 o'][512 k'], o'=so*256+o, k'=si*256+ci
// so=0,si=0: re ; so=0,si=1: -im ; so=1,si=0: im ; so=1,si=1: re
__global__ __launch_bounds__(256) void build_wx_k(const float* wspec, _Float16* Wx){
    __shared__ float t[32][65];
    int o = blockIdx.x;
    int ci0 = blockIdx.y * 32;
    int layer = blockIdx.z / 6;
    int l0 = (blockIdx.z % 6) * 32;
    int tid = threadIdx.x;
    {
        int ci = ci0 + (tid >> 3);
        int e0 = (tid & 7) * 8;
        const float* src = wspec + ((((long long)layer*256 + ci)*256 + o)*180 + l0)*2;
        for (int e = e0; e < e0+8; e++){
            if (l0*2 + e < 360) t[tid>>3][e] = src[e];
        }
    }
    __syncthreads();
    int ci_off = tid & 31, idx = tid >> 5;
    #pragma unroll
    for (int r = 0; r < 4; r++){
        int l = l0 + idx + 8*r;
        if (l >= 180) continue;
        float re = t[ci_off][(l-l0)*2];
        float im = t[ci_off][(l-l0)*2+1];
        long long rb = (((long long)layer*180 + l)*512 + o)*512 + ci0 + ci_off;
        Wx[rb]                = (_Float16)re;
        Wx[rb + 256]          = (_Float16)(-im);
        Wx[rb + 131072]       = (_Float16)im;
        Wx[rb + 131072 + 256] = (_Float16)re;
    }
}

// XF [46080 i][362 (s*181+m)] -> xfm [m][s][c][192(h)] : linear i = c*180+h
__global__ __launch_bounds__(256) void p1_k(const _Float16* XF, _Float16* xfm){
    __shared__ _Float16 t[32][33];
    int s = blockIdx.z;
    int m0 = blockIdx.x*32, i0 = blockIdx.y*32;
    int tx = threadIdx.x & 31, ty = threadIdx.x >> 5;
    #pragma unroll
    for (int q=0;q<4;q++){
        int i = i0+ty+8*q, m = m0+tx;
        if (m < 181) t[ty+8*q][tx] = XF[(long long)i*362 + s*181 + m];
    }
    __syncthreads();
    #pragma unroll
    for (int q=0;q<4;q++){
        int m = m0+ty+8*q, i = i0+tx;
        if (m < 181){
            int c = i/180, h = i%180;
            xfm[(long long)m*98304 + s*49152 + c*192 + h] = t[tx][ty+8*q];
        }
    }
}

// c2 [l][o'][m] (ld 181, per-l 92672) -> c3 [m][o'][192(l)]
__global__ __launch_bounds__(256) void plm_k(const _Float16* c2, _Float16* c3){
    __shared__ _Float16 t[32][33];
    int cs = blockIdx.z;
    int m0 = blockIdx.x*32, l0 = blockIdx.y*32;
    int tx = threadIdx.x & 31, ty = threadIdx.x >> 5;
    #pragma unroll
    for (int q=0;q<4;q++){
        int l = l0+ty+8*q, m = m0+tx;
        if (l<180 && m<181) t[ty+8*q][tx] = c2[(long long)l*92672 + cs*181 + m];
    }
    __syncthreads();
    #pragma unroll
    for (int q=0;q<4;q++){
        int m = m0+ty+8*q, l = l0+tx;
        if (m<181 && l<180) c3[(long long)m*98304 + cs*192 + l] = t[tx][ty+8*q];
    }
}

// Z [m][o'][180(h)] -> XI [(c*180+h)][368(s*181+m)]
__global__ __launch_bounds__(256) void p2_k(const _Float16* Z, _Float16* XI){
    __shared__ _Float16 t[32][33];
    int cs = blockIdx.z; int c = cs & 255, s = cs >> 8;
    int m0 = blockIdx.x*32, h0 = blockIdx.y*32;
    int tx = threadIdx.x & 31, ty = threadIdx.x >> 5;
    #pragma unroll
    for (int q=0;q<4;q++){
        int m = m0+ty+8*q, h = h0+tx;
        if (m<181 && h<180) t[ty+8*q][tx] = Z[(long long)m*92160 + cs*180 + h];
    }
    __syncthreads();
    #pragma unroll
    for (int q=0;q<4;q++){
        int h = h0+ty+8*q, m = m0+tx;
        if (h<180 && m<181) XI[((long long)c*180 + h)*368 + s*181 + m] = t[tx][ty+8*q];
    }
}

extern "C" void kernel_launch(void* const* d_in, const int* in_sizes, int n_in,
                              void* d_out, int out_size, void* d_ws, size_t ws_size,
                              hipStream_t stream){
    const float* x      = (const float*)d_in[0];
    const float* pct    = (const float*)d_in[1];
    const float* pctinv = (const float*)d_in[2];
    const float* wspec  = (const float*)d_in[3];
    const float* winner = (const float*)d_in[4];
    const float* wfc1   = (const float*)d_in[5];
    const float* wfc2   = (const float*)d_in[6];
    const float* wout   = (const float*)d_in[7];
    float* outp = (float*)d_out;

    _Float16* wsh      = (_Float16*)d_ws;
    _Float16* Wx       = wsh;
    _Float16* X_t      = wsh + 94371840LL;
    _Float16* S1       = wsh + 110960640LL;
    _Float16* S2       = wsh + 128753664LL;
    _Float16* S3       = wsh + 146546688LL;
    _Float16* pct16    = wsh + 164339712LL;
    _Float16* pctinvT  = wsh + 170595072LL;
    _Float16* fwdTwT   = wsh + 176850432LL;
    _Float16* invTwT   = wsh + 176980752LL;
    _Float16* winner16 = wsh + 177113232LL;
    _Float16* wfc116   = winner16 + 131072;
    _Float16* wfc216   = wfc116 + 262144;
    _Float16* wout16   = wfc216 + 262144;

    // ---- setup ----
    transpose_k<float><<<dim3(2025,8), 256, 0, stream>>>(x, X_t, 256, 64800);
    build_tw16_k<<<518, 256, 0, stream>>>(fwdTwT, invTwT);
    cvt_pct_k<<<22908, 256, 0, stream>>>(pct, pct16);
    cvt_pctinvT_k<<<dim3(6,6,181), 256, 0, stream>>>(pctinv, pctinvT);
    build_wx_k<<<dim3(256,8,12), 256, 0, stream>>>(wspec, Wx);
    cast_k<<<512, 256, 0, stream>>>(winner, winner16, 131072);
    cast_k<<<1024, 256, 0, stream>>>(wfc1, wfc116, 262144);
    cast_k<<<1024, 256, 0, stream>>>(wfc2, wfc216, 262144);
    cast_k<<<128, 256, 0, stream>>>(wout, wout16, 32768);

    for (int layer = 0; layer < 2; layer++){
        _Float16 *Xc = S1, *XF = S2, *xfm = S3, *spec = S1, *c2 = S2, *c3 = S3;
        _Float16 *Z = S1, *XI = S2, *Yc = S3, *Y_t = S1, *H_t = S2;
        GemmP p;

        // T1: X_t [hw][c] -> Xc [c][hw]
        transpose_k<_Float16><<<dim3(8,2025), 256, 0, stream>>>(X_t, Xc, 64800, 256);

        // DFT: [46080 x 360] x fwdTwT^T -> XF [46080][362]
        p.A = Xc; p.Bt = fwdTwT; p.C = XF;
        p.aBS = 0; p.bBS = 0; p.cBS = 0;
        p.lda = 360; p.ldb = 360; p.ldc = 362;
        p.I = 46080; p.J = 362; p.K = 360;
        mfma_gemm<0,0,_Float16><<<dim3(3,360,1), 256, 0, stream>>>(p);

        // P1: XF -> xfm [m][s][c][192]
        p1_k<<<dim3(6,1440,2), 256, 0, stream>>>(XF, xfm);

        // fwd Legendre (batch m): pct16[m] [180 l][192] x xfm[m] [512 cs][192] -> spec [l][m][cs]
        p.A = pct16; p.Bt = xfm; p.C = spec;
        p.aBS = 34560; p.bBS = 98304; p.cBS = 512;
        p.lda = 192; p.ldb = 192; p.ldc = 92672;
        p.I = 180; p.J = 512; p.K = 180;
        mfma_gemm<0,0,_Float16><<<dim3(4,2,181), 256, 0, stream>>>(p);

        // dhconv (batch l): Wx[l] [512][512] x spec[l] [181 m][512] -> c2 [l][o'][m]
        p.A = Wx + (long long)layer*47185920LL; p.Bt = spec; p.C = c2;
        p.aBS = 262144; p.bBS = 92672; p.cBS = 92672;
        p.lda = 512; p.ldb = 512; p.ldc = 181;
        p.I = 512; p.J = 181; p.K = 512;
        mfma_gemm<0,0,_Float16><<<dim3(2,4,180), 256, 0, stream>>>(p);

        // permute: c2 [l][o'][m] -> c3 [m][o'][192(l)]
        plm_k<<<dim3(6,6,512), 256, 0, stream>>>(c2, c3);

        // inv Legendre (batch m): c3[m] [512 o'][192] x pctinvT[m] [180 h][192] -> Z [m][o'][h]
        p.A = c3; p.Bt = pctinvT; p.C = Z;
        p.aBS = 98304; p.bBS = 34560; p.cBS = 92160;
        p.lda = 192; p.ldb = 192; p.ldc = 180;
        p.I = 512; p.J = 180; p.K = 180;
        mfma_gemm<0,0,_Float16><<<dim3(2,4,181), 256, 0, stream>>>(p);

        // P2: Z -> XI [(c,h)][368]
        p2_k<<<dim3(6,6,512), 256, 0, stream>>>(Z, XI);

        // iDFT: XI [46080][362] x invTwT [360 w][368] -> Yc [46080][360]
        p.A = XI; p.Bt = invTwT; p.C = Yc;
        p.aBS = 0; p.bBS = 0; p.cBS = 0;
        p.lda = 368; p.ldb = 368; p.ldc = 360;
        p.I = 46080; p.J = 360; p.K = 362;
        mfma_gemm<0,0,_Float16><<<dim3(3,360,1), 256, 0, stream>>>(p);

        // T2: Yc [c][hw] -> Y_t [hw][c]
        transpose_k<_Float16><<<dim3(2025,8), 256, 0, stream>>>(Yc, Y_t, 256, 64800);

        // inner skip: gelu(winner @ X_t + Y_t) -> Y_t (trans store [hw][o])
        p.A = winner16 + (long long)layer*65536; p.Bt = X_t; p.C = Y_t;
        p.aBS = 0; p.bBS = 0; p.cBS = 0;
        p.lda = 256; p.ldb = 256; p.ldc = 256;
        p.I = 256; p.J = 64800; p.K = 256;
        mfma_gemm<1,3,_Float16><<<dim3(507,2,1), 256, 0, stream>>>(p);

        // fc1 + gelu -> H_t [hw][512]
        p.A = wfc116 + (long long)layer*131072; p.Bt = Y_t; p.C = H_t;
        p.lda = 256; p.ldb = 256; p.ldc = 512;
        p.I = 512; p.J = 64800; p.K = 256;
        mfma_gemm<1,1,_Float16><<<dim3(507,4,1), 256, 0, stream>>>(p);

        // fc2 + residual + gelu -> X_t (in-place epilogue)
        p.A = wfc216 + (long long)layer*131072; p.Bt = H_t; p.C = X_t;
        p.lda = 512; p.ldb = 512; p.ldc = 256;
        p.I = 256; p.J = 64800; p.K = 512;
        mfma_gemm<1,3,_Float16><<<dim3(507,2,1), 256, 0, stream>>>(p);
    }

    // final: wout [128][256] x X_t -> d_out f32 [128][64800]
    GemmP p;
    p.A = wout16; p.Bt = X_t; p.C = outp;
    p.aBS = 0; p.bBS = 0; p.cBS = 0;
    p.lda = 256; p.ldb = 256; p.ldc = 64800;
    p.I = 128; p.J = 64800; p.K = 256;
    mfma_gemm<0,0,float><<<dim3(507,1,1), 256, 0, stream>>>(p);
}

// Round 3
// 1409.802 us; speedup vs baseline: 4.0535x; 1.0773x over previous
//
#include <hip/hip_runtime.h>
#include <hip/hip_bf16.h>
#include <math.h>

typedef _Float16 half8 __attribute__((ext_vector_type(8)));
typedef _Float16 half4v __attribute__((ext_vector_type(4)));
typedef float floatx4 __attribute__((ext_vector_type(4)));

__device__ __forceinline__ float gelu_f(float x){
    return 0.5f * x * (1.0f + erff(x * 0.70710678118654752440f));
}

typedef __attribute__((address_space(1))) const unsigned int gu32;
typedef __attribute__((address_space(3))) unsigned int lu32;
__device__ __forceinline__ void gl16(const void* g, void* l){
    __builtin_amdgcn_global_load_lds((gu32*)g, (lu32*)l, 16, 0, 0);
}

// ---------------- generic f16 MFMA GEMM ----------------
// C[i][j] = sum_k A[i][k] * Bt[j][k]   (A,Bt rows 16B-aligned, K % 32 == 0,
// all K-tail/pad regions of A,Bt are ZERO; OOB rows readable garbage)
// SM: 0 row store C[i*ldc+j]; 1 trans store C[j*ldc+i..i+3]; 2 spec-dual
// EPI bits (SM1): 1 gelu, 2 add C-old, 4 add D[i*ldd+j], 8 dual-store Xc
struct GemmP {
    const _Float16* A; const _Float16* Bt; void* C; void* C2; const _Float16* D;
    long long aBS, bBS, cBS;
    int lda, ldb, ldc, ldd;
    int I, J, K;
};

template<int SM, int EPI, typename CT>
__global__ __launch_bounds__(256, 3) void mfma_gemm(GemmP p){
    __shared__ __align__(16) _Float16 As[128][32];
    __shared__ __align__(16) _Float16 Bs[128][32];
    const int tid = threadIdx.x, lane = tid & 63, wave = tid >> 6;
    const int wr = wave >> 1, wc = wave & 1;
    const int bj = blockIdx.x, bi = blockIdx.y, bz = blockIdx.z;
    const _Float16* A  = p.A  + (long long)bz * p.aBS;
    const _Float16* Bt = p.Bt + (long long)bz * p.bBS;
    CT* C = (CT*)p.C + (long long)bz * p.cBS;

    const int srow = wave*16 + (lane >> 2);
    const _Float16* Ag = A  + (long long)(bi*128 + srow)*p.lda + (lane & 3)*8;
    const _Float16* Bg = Bt + (long long)(bj*128 + srow)*p.ldb + (lane & 3)*8;
    const long long a64 = (long long)64 * p.lda, b64 = (long long)64 * p.ldb;
    _Float16* AsW = &As[0][0] + wave*512;   // 1024 B per wave
    _Float16* BsW = &Bs[0][0] + wave*512;

    floatx4 acc[4][4];
    #pragma unroll
    for (int a=0;a<4;a++)
        #pragma unroll
        for (int b=0;b<4;b++) acc[a][b] = (floatx4){0.f,0.f,0.f,0.f};

    const int la = lane & 15, lb = lane >> 4;

    for (int k0 = 0; k0 < p.K; k0 += 32){
        gl16(Ag + k0,       AsW);
        gl16(Ag + k0 + a64, AsW + 2048);
        gl16(Bg + k0,       BsW);
        gl16(Bg + k0 + b64, BsW + 2048);
        __syncthreads();

        half8 af[4], bf[4];
        #pragma unroll
        for (int f=0; f<4; f++) af[f] = *(const half8*)&As[wr*64 + f*16 + la][lb*8];
        #pragma unroll
        for (int f=0; f<4; f++) bf[f] = *(const half8*)&Bs[wc*64 + f*16 + la][lb*8];
        #pragma unroll
        for (int mi=0; mi<4; mi++)
            #pragma unroll
            for (int nj=0; nj<4; nj++)
                acc[mi][nj] = __builtin_amdgcn_mfma_f32_16x16x32_f16(
                    af[mi], bf[nj], acc[mi][nj], 0, 0, 0);
        __syncthreads();
    }

    // epilogue. C/D: col = lane&15, row = (lane>>4)*4 + reg
    #pragma unroll
    for (int mi=0; mi<4; mi++){
        const int ibase = bi*128 + wr*64 + mi*16 + lb*4;
        #pragma unroll
        for (int nj=0; nj<4; nj++){
            const int j = bj*128 + wc*64 + nj*16 + la;
            if (j >= p.J) continue;
            if (SM == 0){
                #pragma unroll
                for (int r=0;r<4;r++){
                    int i = ibase + r;
                    if (i >= p.I) continue;
                    C[(long long)i*p.ldc + j] = (CT)acc[mi][nj][r];
                }
            } else if (SM == 2){
                _Float16* C2p = (_Float16*)p.C2 + (long long)bz*p.cBS;
                #pragma unroll
                for (int r=0;r<4;r++){
                    int i = ibase + r;
                    if (i >= p.I) continue;
                    float v = acc[mi][nj][r];
                    ((_Float16*)C)[(long long)i*p.ldc + j]   = (_Float16)((j & 1) ? -v : v);
                    C2p[(long long)i*p.ldc + (j ^ 1)]        = (_Float16)v;
                }
            } else { // SM == 1
                CT* cp = C + (long long)j*p.ldc + ibase;
                float v[4];
                #pragma unroll
                for (int r=0;r<4;r++) v[r] = acc[mi][nj][r];
                if (EPI & 2){
                    half4v old = *(const half4v*)(const void*)cp;
                    #pragma unroll
                    for (int r=0;r<4;r++) v[r] += (float)old[r];
                }
                if (EPI & 4){
                    #pragma unroll
                    for (int r=0;r<4;r++)
                        v[r] += (float)p.D[(long long)(ibase + r)*p.ldd + j];
                }
                if (EPI & 1){
                    #pragma unroll
                    for (int r=0;r<4;r++) v[r] = gelu_f(v[r]);
                }
                half4v ov;
                #pragma unroll
                for (int r=0;r<4;r++) ov[r] = (_Float16)v[r];
                *(half4v*)(void*)cp = ov;
                if (EPI & 8){
                    int h = j/360, w = j - h*360;
                    _Float16* xc = (_Float16*)p.C2;
                    #pragma unroll
                    for (int r=0;r<4;r++)
                        xc[(long long)(ibase + r)*69120 + h*384 + w] = ov[r];
                }
            }
        }
    }
}

// ---------------- setup / bridge kernels ----------------
// x f32 [R][Cc] -> out f16 [Cc][R]
template<typename TI>
__global__ __launch_bounds__(256) void transpose_k(const TI* in, _Float16* out, int R, int Cc){
    __shared__ float t[32][33];
    int c0 = blockIdx.x*32, r0 = blockIdx.y*32;
    int tx = threadIdx.x & 31, ty = threadIdx.x >> 5;
    #pragma unroll
    for (int q=0;q<4;q++){
        int r = r0 + ty + 8*q, c = c0 + tx;
        if (r < R && c < Cc) t[ty+8*q][tx] = (float)in[(long long)r*Cc + c];
    }
    __syncthreads();
    #pragma unroll
    for (int q=0;q<4;q++){
        int c = c0 + ty + 8*q, r = r0 + tx;
        if (c < Cc && r < R) out[(long long)c*R + r] = (_Float16)t[tx][ty+8*q];
    }
}

// x f32 [c][h][w] -> Xc f16 [c*180+h][384] (pads pre-zeroed)
__global__ __launch_bounds__(256) void t0_k(const float* x, _Float16* Xc){
    long long id = (long long)blockIdx.x*256 + threadIdx.x;
    if (id < 16588800LL){
        int row = (int)(id / 360), w = (int)(id % 360);
        Xc[(long long)row*384 + w] = (_Float16)x[id];
    }
}

__global__ __launch_bounds__(256) void cast_k(const float* in, _Float16* out, int n){
    int i = blockIdx.x*256 + threadIdx.x;
    if (i < n) out[i] = (_Float16)in[i];
}

// pct [m][l][h] f32 -> pct16 [m][l][192] (pad zero)
__global__ __launch_bounds__(256) void cvt_pct_k(const float* in, _Float16* out){
    int id = blockIdx.x*256 + threadIdx.x;
    if (id >= 181*180*192) return;
    int m = id / 34560, r = id % 34560;
    int l = r / 192, h = r % 192;
    out[id] = (h < 180) ? (_Float16)in[(long long)m*32400 + l*180 + h] : (_Float16)0.f;
}

// pctinv [m][l][h] -> pctinvT [m][h][192(l)] (pad zero)
__global__ __launch_bounds__(256) void cvt_pctinvT_k(const float* in, _Float16* out){
    __shared__ float t[32][33];
    int m = blockIdx.z;
    int h0 = blockIdx.x*32, l0 = blockIdx.y*32;
    int tx = threadIdx.x & 31, ty = threadIdx.x >> 5;
    #pragma unroll
    for (int q=0;q<4;q++){
        int l = l0+ty+8*q, h = h0+tx;
        t[ty+8*q][tx] = (l < 180 && h < 180) ? in[(long long)m*32400 + l*180 + h] : 0.f;
    }
    __syncthreads();
    #pragma unroll
    for (int q=0;q<4;q++){
        int h = h0+ty+8*q, l = l0+tx;
        if (h < 180 && l < 192) out[(long long)m*34560 + h*192 + l] = (_Float16)t[tx][ty+8*q];
    }
}

// fwdTwT [384 rows (s*181+m)][384 (w)], invTwT [384 rows (w)][384 (s*181+m)]
__global__ __launch_bounds__(256) void build_tw16_k(_Float16* fwdTwT, _Float16* invTwT){
    int id = blockIdx.x*256 + threadIdx.x;
    if (id >= 147456) return;
    {
        int j = id / 384, w = id % 384;
        float v = 0.f;
        if (j < 362 && w < 360){
            int m = (j < 181) ? j : j - 181;
            float ang = 6.28318530717958647692f * (float)((w*m) % 360) / 360.f;
            v = (j < 181) ? cosf(ang) : -sinf(ang);
        }
        fwdTwT[id] = (_Float16)v;
    }
    {
        int w = id / 384, k = id % 384;
        float v = 0.f;
        if (w < 360 && k < 362){
            int m = (k < 181) ? k : k - 181;
            float ang = 6.28318530717958647692f * (float)((w*m) % 360) / 360.f;
            float sc = (m == 0 || m == 180) ? (1.f/360.f) : (2.f/360.f);
            v = (k < 181) ? sc*cosf(ang) : -sc*sinf(ang);
        }
        invTwT[id] = (_Float16)v;
    }
}

// wspec [layer][ci][o][l][s] -> Wc [layer][l][o 256][k'=2ci+s]
__global__ __launch_bounds__(256) void build_wc_k(const float* wspec, _Float16* Wc){
    __shared__ float t[64][33];
    int o = blockIdx.x, ci0 = blockIdx.y*64;
    int lz = blockIdx.z, layer = lz/12, l0 = (lz%12)*16;
    int tid = threadIdx.x;
    {
        int cir = tid >> 2, c0 = (tid & 3)*8;
        const float* src = wspec + ((long long)layer*256 + ci0 + cir)*92160
                                 + (long long)o*360 + 2*l0;
        #pragma unroll
        for (int e=0;e<8;e++){
            int l2 = c0 + e;
            t[cir][l2 & 31] = (2*l0 + l2 < 360) ? src[l2] : 0.f;
        }
    }
    __syncthreads();
    int g = tid >> 6, lane = tid & 63;
    #pragma unroll
    for (int q=0;q<4;q++){
        int lloc = g*4 + q, l = l0 + lloc;
        if (l >= 180) continue;
        float re = t[lane][2*lloc], im = t[lane][2*lloc+1];
        union { unsigned int u; _Float16 h[2]; } pk;
        pk.h[0] = (_Float16)re; pk.h[1] = (_Float16)im;
        *(unsigned int*)&Wc[(((long long)layer*180 + l)*256 + o)*512 + 2*(ci0 + lane)] = pk.u;
    }
}

// XF [46080 (c,h)][362 (s*181+m)] -> xfm [m][2c+s][192(h)]
__global__ __launch_bounds__(256) void p1_k(const _Float16* XF, _Float16* xfm){
    __shared__ _Float16 t[32][33];
    int s = blockIdx.z;
    int m0 = blockIdx.x*32, i0 = blockIdx.y*32;
    int tx = threadIdx.x & 31, ty = threadIdx.x >> 5;
    #pragma unroll
    for (int q=0;q<4;q++){
        int i = i0+ty+8*q, m = m0+tx;
        if (m < 181) t[ty+8*q][tx] = XF[(long long)i*362 + s*181 + m];
    }
    __syncthreads();
    #pragma unroll
    for (int q=0;q<4;q++){
        int m = m0+ty+8*q, i = i0+tx;
        if (m < 181){
            int c = i/180, h = i%180;
            xfm[(long long)m*98304 + (2*c + s)*192 + h] = t[tx][ty+8*q];
        }
    }
}

// c2 [l][o2][m] (ld 181) -> c3 [m][o2][192(l)]
__global__ __launch_bounds__(256) void plm_k(const _Float16* c2, _Float16* c3){
    __shared__ _Float16 t[32][33];
    int cs = blockIdx.z;
    int m0 = blockIdx.x*32, l0 = blockIdx.y*32;
    int tx = threadIdx.x & 31, ty = threadIdx.x >> 5;
    #pragma unroll
    for (int q=0;q<4;q++){
        int l = l0+ty+8*q, m = m0+tx;
        if (l < 180 && m < 181) t[ty+8*q][tx] = c2[(long long)l*92672 + cs*181 + m];
    }
    __syncthreads();
    #pragma unroll
    for (int q=0;q<4;q++){
        int m = m0+ty+8*q, l = l0+tx;
        if (m < 181 && l < 180) c3[(long long)m*98304 + cs*192 + l] = t[tx][ty+8*q];
    }
}

// Z [m][o2][180(h)] -> XI [(c*180+h)][384 (s*181+m)]
__global__ __launch_bounds__(256) void p2_k(const _Float16* Z, _Float16* XI){
    __shared__ _Float16 t[32][33];
    int cs = blockIdx.z; int c = cs & 255, s = cs >> 8;
    int m0 = blockIdx.x*32, h0 = blockIdx.y*32;
    int tx = threadIdx.x & 31, ty = threadIdx.x >> 5;
    #pragma unroll
    for (int q=0;q<4;q++){
        int m = m0+ty+8*q, h = h0+tx;
        if (m < 181 && h < 180) t[ty+8*q][tx] = Z[(long long)m*92160 + cs*180 + h];
    }
    __syncthreads();
    #pragma unroll
    for (int q=0;q<4;q++){
        int h = h0+ty+8*q, m = m0+tx;
        if (h < 180 && m < 181) XI[((long long)c*180 + h)*384 + s*181 + m] = t[tx][ty+8*q];
    }
}

// zero XI cols [352,384) (p2 rewrites 352..361 after)
__global__ __launch_bounds__(256) void zero_xi_k(_Float16* XI){
    int id = blockIdx.x*256 + threadIdx.x;
    if (id < 1474560){
        int row = id >> 5, k = 352 + (id & 31);
        XI[(long long)row*384 + k] = (_Float16)0.f;
    }
}

extern "C" void kernel_launch(void* const* d_in, const int* in_sizes, int n_in,
                              void* d_out, int out_size, void* d_ws, size_t ws_size,
                              hipStream_t stream){
    const float* x      = (const float*)d_in[0];
    const float* pct    = (const float*)d_in[1];
    const float* pctinv = (const float*)d_in[2];
    const float* wspec  = (const float*)d_in[3];
    const float* winner = (const float*)d_in[4];
    const float* wfc1   = (const float*)d_in[5];
    const float* wfc2   = (const float*)d_in[6];
    const float* wout   = (const float*)d_in[7];
    float* outp = (float*)d_out;

    _Float16* wsh = (_Float16*)d_ws;
    _Float16* Wc       = wsh;                    // 47,185,920
    _Float16* X_t      = wsh + 47185920LL;       // 16,588,800
    _Float16* Xc       = wsh + 63774720LL;       // 17,694,720 (memset once)
    _Float16* P        = wsh + 81469440LL;       // 17,793,024 xfm / c3 (memset once)
    _Float16* BXZ      = wsh + 99262464LL;       // 16,680,960 XF / spec2 / Z
    _Float16* BSY      = wsh + 115943424LL;      // 16,680,960 spec1 / Yc
    _Float16* BCY      = wsh + 132624384LL;      // 16,680,960 c2 / Y_t
    _Float16* BHX      = wsh + 149305344LL;      // 33,177,600 XI / H_t
    _Float16* pct16    = wsh + 182482944LL;      // 6,255,360
    _Float16* pctinvT  = wsh + 188738304LL;      // 6,255,360
    _Float16* fwdTwT   = wsh + 194993664LL;      // 147,456
    _Float16* invTwT   = wsh + 195141120LL;      // 147,456
    _Float16* winner16 = wsh + 195288576LL;      // 131,072
    _Float16* wfc116   = wsh + 195419648LL;      // 262,144
    _Float16* wfc216   = wsh + 195681792LL;      // 262,144
    _Float16* wout16   = wsh + 195943936LL;      // 32,768  (+slack)

    // ---- setup ----
    hipMemsetAsync(Xc, 0, 17694720LL*2, stream);
    hipMemsetAsync(P,  0, 17793024LL*2, stream);
    transpose_k<float><<<dim3(2025,8), 256, 0, stream>>>(x, X_t, 256, 64800);
    t0_k<<<64800, 256, 0, stream>>>(x, Xc);
    build_tw16_k<<<576, 256, 0, stream>>>(fwdTwT, invTwT);
    cvt_pct_k<<<24435, 256, 0, stream>>>(pct, pct16);
    cvt_pctinvT_k<<<dim3(6,6,181), 256, 0, stream>>>(pctinv, pctinvT);
    build_wc_k<<<dim3(256,4,24), 256, 0, stream>>>(wspec, Wc);
    cast_k<<<512, 256, 0, stream>>>(winner, winner16, 131072);
    cast_k<<<1024, 256, 0, stream>>>(wfc1, wfc116, 262144);
    cast_k<<<1024, 256, 0, stream>>>(wfc2, wfc216, 262144);
    cast_k<<<128, 256, 0, stream>>>(wout, wout16, 32768);

    for (int layer = 0; layer < 2; layer++){
        _Float16 *XF = BXZ, *xfm = P, *spec1 = BSY, *spec2 = BXZ, *c2 = BCY;
        _Float16 *c3 = P, *Z = BXZ, *XI = BHX, *Yc = BSY, *Y_t = BCY, *H_t = BHX;
        GemmP p; p.C2 = nullptr; p.D = nullptr; p.ldd = 0;

        // DFT: Xc [46080][384] x fwdTwT [362][384] -> XF [46080][362]
        p.A = Xc; p.Bt = fwdTwT; p.C = XF;
        p.aBS = 0; p.bBS = 0; p.cBS = 0;
        p.lda = 384; p.ldb = 384; p.ldc = 362;
        p.I = 46080; p.J = 362; p.K = 384;
        mfma_gemm<0,0,_Float16><<<dim3(3,360,1), 256, 0, stream>>>(p);

        // P1: XF -> xfm [m][2c+s][192]
        p1_k<<<dim3(6,1440,2), 256, 0, stream>>>(XF, xfm);

        // fwd Legendre (batch m): pct16[m][180 l][192] x xfm[m][512][192]
        //   -> spec1/spec2 [l][m][512] (dual, signed)
        p.A = pct16; p.Bt = xfm; p.C = spec1; p.C2 = spec2;
        p.aBS = 34560; p.bBS = 98304; p.cBS = 512;
        p.lda = 192; p.ldb = 192; p.ldc = 92672;
        p.I = 180; p.J = 512; p.K = 192;
        mfma_gemm<2,0,_Float16><<<dim3(4,2,181), 256, 0, stream>>>(p);
        p.C2 = nullptr;

        // dhconv (batch l): Wc[l][256][512] x spec1/2 [m][512] -> c2 [l][o2][m]
        p.A = Wc + (long long)layer*23592960LL; p.Bt = spec1; p.C = c2;
        p.aBS = 131072; p.bBS = 92672; p.cBS = 92672;
        p.lda = 512; p.ldb = 512; p.ldc = 181;
        p.I = 256; p.J = 181; p.K = 512;
        mfma_gemm<0,0,_Float16><<<dim3(2,2,180), 256, 0, stream>>>(p);
        p.Bt = spec2; p.C = c2 + 46336;  // imag rows at o2 = 256..511
        mfma_gemm<0,0,_Float16><<<dim3(2,2,180), 256, 0, stream>>>(p);

        // permute: c2 -> c3 [m][o2][192(l)]
        plm_k<<<dim3(6,6,512), 256, 0, stream>>>(c2, c3);

        // inv Legendre (batch m): c3[m][512][192] x pctinvT[m][180 h][192] -> Z [m][o2][h]
        p.A = c3; p.Bt = pctinvT; p.C = Z;
        p.aBS = 98304; p.bBS = 34560; p.cBS = 92160;
        p.lda = 192; p.ldb = 192; p.ldc = 180;
        p.I = 512; p.J = 180; p.K = 192;
        mfma_gemm<0,0,_Float16><<<dim3(2,4,181), 256, 0, stream>>>(p);

        // P2: Z -> XI [(c,h)][384]
        zero_xi_k<<<5760, 256, 0, stream>>>(XI);
        p2_k<<<dim3(6,6,512), 256, 0, stream>>>(Z, XI);

        // iDFT: XI [46080][384] x invTwT [360][384] -> Yc [46080][360]
        p.A = XI; p.Bt = invTwT; p.C = Yc;
        p.aBS = 0; p.bBS = 0; p.cBS = 0;
        p.lda = 384; p.ldb = 384; p.ldc = 360;
        p.I = 46080; p.J = 360; p.K = 384;
        mfma_gemm<0,0,_Float16><<<dim3(3,360,1), 256, 0, stream>>>(p);

        // inner skip: Y_t[hw][256] = gelu(winner@X_t + Yc)
        p.A = winner16 + (long long)layer*65536; p.Bt = X_t; p.C = Y_t;
        p.D = Yc; p.ldd = 64800;
        p.lda = 256; p.ldb = 256; p.ldc = 256;
        p.I = 256; p.J = 64800; p.K = 256;
        mfma_gemm<1,5,_Float16><<<dim3(507,2,1), 256, 0, stream>>>(p);
        p.D = nullptr; p.ldd = 0;

        // fc1 + gelu -> H_t [hw][512]
        p.A = wfc116 + (long long)layer*131072; p.Bt = Y_t; p.C = H_t;
        p.lda = 256; p.ldb = 256; p.ldc = 512;
        p.I = 512; p.J = 64800; p.K = 256;
        mfma_gemm<1,1,_Float16><<<dim3(507,4,1), 256, 0, stream>>>(p);

        // fc2 + residual + gelu -> X_t ; layer 0 also dual-stores next Xc
        p.A = wfc216 + (long long)layer*131072; p.Bt = H_t; p.C = X_t;
        p.lda = 512; p.ldb = 512; p.ldc = 256;
        p.I = 256; p.J = 64800; p.K = 512;
        if (layer == 0){
            p.C2 = Xc;
            mfma_gemm<1,11,_Float16><<<dim3(507,2,1), 256, 0, stream>>>(p);
            p.C2 = nullptr;
        } else {
            mfma_gemm<1,3,_Float16><<<dim3(507,2,1), 256, 0, stream>>>(p);
        }
    }

    // final: wout16 [128][256] x X_t -> d_out f32 [128][64800]
    GemmP p; p.C2 = nullptr; p.D = nullptr; p.ldd = 0;
    p.A = wout16; p.Bt = X_t; p.C = outp;
    p.aBS = 0; p.bBS = 0; p.cBS = 0;
    p.lda = 256; p.ldb = 256; p.ldc = 64800;
    p.I = 128; p.J = 64800; p.K = 256;
    mfma_gemm<0,0,float><<<dim3(507,1,1), 256, 0, stream>>>(p);
}

// Round 4
// 1326.044 us; speedup vs baseline: 4.3095x; 1.0632x over previous
//
#include <hip/hip_runtime.h>
#include <hip/hip_bf16.h>
#include <math.h>

typedef _Float16 half8 __attribute__((ext_vector_type(8)));
typedef _Float16 half4v __attribute__((ext_vector_type(4)));
typedef float floatx4 __attribute__((ext_vector_type(4)));

__device__ __forceinline__ float gelu_f(float x){
    return 0.5f * x * (1.0f + erff(x * 0.70710678118654752440f));
}

typedef __attribute__((address_space(1))) const unsigned int gu32;
typedef __attribute__((address_space(3))) unsigned int lu32;
__device__ __forceinline__ void gl16(const void* g, void* l){
    __builtin_amdgcn_global_load_lds((gu32*)g, (lu32*)l, 16, 0, 0);
}

// ---------------- generic f16 MFMA GEMM ----------------
// C[i][j] = sum_k A[i][k] * Bt[j][k]   (A,Bt rows 16B-aligned, K % 32 == 0,
// all K-tail/pad regions of A,Bt are ZERO; OOB rows readable garbage)
// SM: 0 row store C[i*ldc+j]; 1 trans store C[j*ldc+i..i+3]; 2 spec-dual;
//     3 dhconv-split (j<181: row i col j ; j>=181: row i+256 col j-181)
// EPI bits (SM1): 1 gelu, 2 add C-old, 4 add D[i*ldd+j], 8 dual-store Xc
struct GemmP {
    const _Float16* A; const _Float16* Bt; void* C; void* C2; const _Float16* D;
    long long aBS, bBS, cBS;
    int lda, ldb, ldc, ldd;
    int I, J, K;
};

template<int SM, int EPI, typename CT>
__global__ __launch_bounds__(256, 3) void mfma_gemm(GemmP p){
    __shared__ __align__(16) _Float16 As[128][32];
    __shared__ __align__(16) _Float16 Bs[128][32];
    const int tid = threadIdx.x, lane = tid & 63, wave = tid >> 6;
    const int wr = wave >> 1, wc = wave & 1;
    const int bj = blockIdx.x, bi = blockIdx.y, bz = blockIdx.z;
    const _Float16* A  = p.A  + (long long)bz * p.aBS;
    const _Float16* Bt = p.Bt + (long long)bz * p.bBS;
    CT* C = (CT*)p.C + (long long)bz * p.cBS;

    const int srow = wave*16 + (lane >> 2);
    const _Float16* Ag = A  + (long long)(bi*128 + srow)*p.lda + (lane & 3)*8;
    const _Float16* Bg = Bt + (long long)(bj*128 + srow)*p.ldb + (lane & 3)*8;
    const long long a64 = (long long)64 * p.lda, b64 = (long long)64 * p.ldb;
    _Float16* AsW = &As[0][0] + wave*512;   // 1024 B per wave
    _Float16* BsW = &Bs[0][0] + wave*512;

    floatx4 acc[4][4];
    #pragma unroll
    for (int a=0;a<4;a++)
        #pragma unroll
        for (int b=0;b<4;b++) acc[a][b] = (floatx4){0.f,0.f,0.f,0.f};

    const int la = lane & 15, lb = lane >> 4;

    for (int k0 = 0; k0 < p.K; k0 += 32){
        gl16(Ag + k0,       AsW);
        gl16(Ag + k0 + a64, AsW + 2048);
        gl16(Bg + k0,       BsW);
        gl16(Bg + k0 + b64, BsW + 2048);
        __syncthreads();

        half8 af[4], bf[4];
        #pragma unroll
        for (int f=0; f<4; f++) af[f] = *(const half8*)&As[wr*64 + f*16 + la][lb*8];
        #pragma unroll
        for (int f=0; f<4; f++) bf[f] = *(const half8*)&Bs[wc*64 + f*16 + la][lb*8];
        #pragma unroll
        for (int mi=0; mi<4; mi++)
            #pragma unroll
            for (int nj=0; nj<4; nj++)
                acc[mi][nj] = __builtin_amdgcn_mfma_f32_16x16x32_f16(
                    af[mi], bf[nj], acc[mi][nj], 0, 0, 0);
        __syncthreads();
    }

    // epilogue. C/D: col = lane&15, row = (lane>>4)*4 + reg
    #pragma unroll
    for (int mi=0; mi<4; mi++){
        const int ibase = bi*128 + wr*64 + mi*16 + lb*4;
        #pragma unroll
        for (int nj=0; nj<4; nj++){
            const int j = bj*128 + wc*64 + nj*16 + la;
            if (j >= p.J) continue;
            if (SM == 0){
                #pragma unroll
                for (int r=0;r<4;r++){
                    int i = ibase + r;
                    if (i >= p.I) continue;
                    C[(long long)i*p.ldc + j] = (CT)acc[mi][nj][r];
                }
            } else if (SM == 2){
                _Float16* C2p = (_Float16*)p.C2 + (long long)bz*p.cBS;
                #pragma unroll
                for (int r=0;r<4;r++){
                    int i = ibase + r;
                    if (i >= p.I) continue;
                    float v = acc[mi][nj][r];
                    ((_Float16*)C)[(long long)i*p.ldc + j]   = (_Float16)((j & 1) ? -v : v);
                    C2p[(long long)i*p.ldc + (j ^ 1)]        = (_Float16)v;
                }
            } else if (SM == 3){
                const int row_add = (j < 181) ? 0 : 256;
                const int col = (j < 181) ? j : j - 181;
                #pragma unroll
                for (int r=0;r<4;r++){
                    int i = ibase + r;
                    if (i >= p.I) continue;
                    C[(long long)(i + row_add)*p.ldc + col] = (CT)acc[mi][nj][r];
                }
            } else { // SM == 1
                CT* cp = C + (long long)j*p.ldc + ibase;
                float v[4];
                #pragma unroll
                for (int r=0;r<4;r++) v[r] = acc[mi][nj][r];
                if (EPI & 2){
                    half4v old = *(const half4v*)(const void*)cp;
                    #pragma unroll
                    for (int r=0;r<4;r++) v[r] += (float)old[r];
                }
                if (EPI & 4){
                    #pragma unroll
                    for (int r=0;r<4;r++)
                        v[r] += (float)p.D[(long long)(ibase + r)*p.ldd + j];
                }
                if (EPI & 1){
                    #pragma unroll
                    for (int r=0;r<4;r++) v[r] = gelu_f(v[r]);
                }
                half4v ov;
                #pragma unroll
                for (int r=0;r<4;r++) ov[r] = (_Float16)v[r];
                *(half4v*)(void*)cp = ov;
                if (EPI & 8){
                    int h = j/360, w = j - h*360;
                    _Float16* xc = (_Float16*)p.C2;
                    #pragma unroll
                    for (int r=0;r<4;r++)
                        xc[(long long)(ibase + r)*69120 + h*384 + w] = ov[r];
                }
            }
        }
    }
}

// ---------------- setup / bridge kernels ----------------
// x f32 [c][hw] -> X_t f16 [hw][256] AND Xc f16 [(c*180+h)][384]
__global__ __launch_bounds__(256) void tx_k(const float* x, _Float16* X_t, _Float16* Xc){
    __shared__ _Float16 t[32][33];
    int p0 = blockIdx.x*32, c0 = blockIdx.y*32;
    int tx = threadIdx.x & 31, ty = threadIdx.x >> 5;
    #pragma unroll
    for (int q=0;q<4;q++){
        int c = c0 + ty + 8*q, hw = p0 + tx;
        _Float16 h = (_Float16)x[(long long)c*64800 + hw];
        t[ty+8*q][tx] = h;
        int hh = hw/360, w = hw - hh*360;
        Xc[((long long)c*180 + hh)*384 + w] = h;
    }
    __syncthreads();
    #pragma unroll
    for (int q=0;q<4;q++){
        int hw = p0 + ty + 8*q, c = c0 + tx;
        X_t[(long long)hw*256 + c] = t[tx][ty+8*q];
    }
}

__global__ __launch_bounds__(256) void cast_k(const float* in, _Float16* out, int n){
    int i = blockIdx.x*256 + threadIdx.x;
    if (i < n) out[i] = (_Float16)in[i];
}

// pct [m][l][h] f32 -> pct16 [m][l][192] (pad zero)
__global__ __launch_bounds__(256) void cvt_pct_k(const float* in, _Float16* out){
    int id = blockIdx.x*256 + threadIdx.x;
    if (id >= 181*180*192) return;
    int m = id / 34560, r = id % 34560;
    int l = r / 192, h = r % 192;
    out[id] = (h < 180) ? (_Float16)in[(long long)m*32400 + l*180 + h] : (_Float16)0.f;
}

// pctinv [m][l][h] -> pctinvT [m][h][192(l)] (pad zero)
__global__ __launch_bounds__(256) void cvt_pctinvT_k(const float* in, _Float16* out){
    __shared__ float t[32][33];
    int m = blockIdx.z;
    int h0 = blockIdx.x*32, l0 = blockIdx.y*32;
    int tx = threadIdx.x & 31, ty = threadIdx.x >> 5;
    #pragma unroll
    for (int q=0;q<4;q++){
        int l = l0+ty+8*q, h = h0+tx;
        t[ty+8*q][tx] = (l < 180 && h < 180) ? in[(long long)m*32400 + l*180 + h] : 0.f;
    }
    __syncthreads();
    #pragma unroll
    for (int q=0;q<4;q++){
        int h = h0+ty+8*q, l = l0+tx;
        if (h < 180 && l < 192) out[(long long)m*34560 + h*192 + l] = (_Float16)t[tx][ty+8*q];
    }
}

// fwdTwT [384 rows (s*181+m)][384 (w)], invTwT [384 rows (w)][384 (s*181+m)]
__global__ __launch_bounds__(256) void build_tw16_k(_Float16* fwdTwT, _Float16* invTwT){
    int id = blockIdx.x*256 + threadIdx.x;
    if (id >= 147456) return;
    {
        int j = id / 384, w = id % 384;
        float v = 0.f;
        if (j < 362 && w < 360){
            int m = (j < 181) ? j : j - 181;
            float ang = 6.28318530717958647692f * (float)((w*m) % 360) / 360.f;
            v = (j < 181) ? cosf(ang) : -sinf(ang);
        }
        fwdTwT[id] = (_Float16)v;
    }
    {
        int w = id / 384, k = id % 384;
        float v = 0.f;
        if (w < 360 && k < 362){
            int m = (k < 181) ? k : k - 181;
            float ang = 6.28318530717958647692f * (float)((w*m) % 360) / 360.f;
            float sc = (m == 0 || m == 180) ? (1.f/360.f) : (2.f/360.f);
            v = (k < 181) ? sc*cosf(ang) : -sc*sinf(ang);
        }
        invTwT[id] = (_Float16)v;
    }
}

// wspec [layer][ci][o][l][s] f32 -> Wc: u32 view Wc32[((layer*180+l)*256+o)*256+ci] = half2(re,im)
// pure u32 transpose per (layer,o): 32x32 LDS tiles, float2 reads, u32 writes
__global__ __launch_bounds__(256) void build_wc_k(const float* wspec, _Float16* Wc){
    __shared__ unsigned int t[32][33];
    int o = blockIdx.x;
    int ci0 = blockIdx.y * 32;
    int z = blockIdx.z, layer = z / 6, l0 = (z % 6) * 32;
    int tx = threadIdx.x & 31, ty = threadIdx.x >> 5;
    unsigned int* Wc32 = (unsigned int*)Wc;
    #pragma unroll
    for (int q=0;q<4;q++){
        int ci = ci0 + ty + 8*q, l = l0 + tx;
        if (l < 180){
            const float2 v = *(const float2*)(wspec +
                ((long long)(layer*256 + ci))*92160 + (long long)o*360 + 2*l);
            union { unsigned int u; _Float16 h[2]; } pk;
            pk.h[0] = (_Float16)v.x; pk.h[1] = (_Float16)v.y;
            t[ty+8*q][tx] = pk.u;
        }
    }
    __syncthreads();
    #pragma unroll
    for (int q=0;q<4;q++){
        int l = l0 + ty + 8*q, ci = ci0 + tx;
        if (l < 180)
            Wc32[(((long long)layer*180 + l)*256 + o)*256 + ci] = t[tx][ty+8*q];
    }
}

// XF [46080 (c,h)][362 (s*181+m)] -> xfm [m][2c+s][192(h)]
__global__ __launch_bounds__(256) void p1_k(const _Float16* XF, _Float16* xfm){
    __shared__ _Float16 t[32][33];
    int s = blockIdx.z;
    int m0 = blockIdx.x*32, i0 = blockIdx.y*32;
    int tx = threadIdx.x & 31, ty = threadIdx.x >> 5;
    #pragma unroll
    for (int q=0;q<4;q++){
        int i = i0+ty+8*q, m = m0+tx;
        if (m < 181) t[ty+8*q][tx] = XF[(long long)i*362 + s*181 + m];
    }
    __syncthreads();
    #pragma unroll
    for (int q=0;q<4;q++){
        int m = m0+ty+8*q, i = i0+tx;
        if (m < 181){
            int c = i/180, h = i%180;
            xfm[(long long)m*98304 + (2*c + s)*192 + h] = t[tx][ty+8*q];
        }
    }
}

// c2 [l][o2][m] (ld 181) -> c3 [m][o2][192(l)]
__global__ __launch_bounds__(256) void plm_k(const _Float16* c2, _Float16* c3){
    __shared__ _Float16 t[32][33];
    int cs = blockIdx.z;
    int m0 = blockIdx.x*32, l0 = blockIdx.y*32;
    int tx = threadIdx.x & 31, ty = threadIdx.x >> 5;
    #pragma unroll
    for (int q=0;q<4;q++){
        int l = l0+ty+8*q, m = m0+tx;
        if (l < 180 && m < 181) t[ty+8*q][tx] = c2[(long long)l*92672 + cs*181 + m];
    }
    __syncthreads();
    #pragma unroll
    for (int q=0;q<4;q++){
        int m = m0+ty+8*q, l = l0+tx;
        if (m < 181 && l < 180) c3[(long long)m*98304 + cs*192 + l] = t[tx][ty+8*q];
    }
}

// Z [m][o2][180(h)] -> XI [(c*180+h)][384 (s*181+m)]
__global__ __launch_bounds__(256) void p2_k(const _Float16* Z, _Float16* XI){
    __shared__ _Float16 t[32][33];
    int cs = blockIdx.z; int c = cs & 255, s = cs >> 8;
    int m0 = blockIdx.x*32, h0 = blockIdx.y*32;
    int tx = threadIdx.x & 31, ty = threadIdx.x >> 5;
    #pragma unroll
    for (int q=0;q<4;q++){
        int m = m0+ty+8*q, h = h0+tx;
        if (m < 181 && h < 180) t[ty+8*q][tx] = Z[(long long)m*92160 + cs*180 + h];
    }
    __syncthreads();
    #pragma unroll
    for (int q=0;q<4;q++){
        int h = h0+ty+8*q, m = m0+tx;
        if (h < 180 && m < 181) XI[((long long)c*180 + h)*384 + s*181 + m] = t[tx][ty+8*q];
    }
}

// zero XI cols [352,384) (p2 rewrites 352..361 after)
__global__ __launch_bounds__(256) void zero_xi_k(_Float16* XI){
    int id = blockIdx.x*256 + threadIdx.x;
    if (id < 1474560){
        int row = id >> 5, k = 352 + (id & 31);
        XI[(long long)row*384 + k] = (_Float16)0.f;
    }
}

extern "C" void kernel_launch(void* const* d_in, const int* in_sizes, int n_in,
                              void* d_out, int out_size, void* d_ws, size_t ws_size,
                              hipStream_t stream){
    const float* x      = (const float*)d_in[0];
    const float* pct    = (const float*)d_in[1];
    const float* pctinv = (const float*)d_in[2];
    const float* wspec  = (const float*)d_in[3];
    const float* winner = (const float*)d_in[4];
    const float* wfc1   = (const float*)d_in[5];
    const float* wfc2   = (const float*)d_in[6];
    const float* wout   = (const float*)d_in[7];
    float* outp = (float*)d_out;

    _Float16* wsh = (_Float16*)d_ws;
    _Float16* Wc       = wsh;                    // 47,185,920
    _Float16* X_t      = wsh + 47185920LL;       // 16,588,800
    _Float16* Xc       = wsh + 63774720LL;       // 17,694,720 (memset once)
    _Float16* P        = wsh + 81469440LL;       // 17,793,024 xfm / c3 (memset once)
    _Float16* R5       = wsh + 99262464LL;       // 33,361,920 XF / spec / XI / Y_t
    _Float16* R6       = wsh + 132624384LL;      // 16,680,960 c2 / Z / Yc
    _Float16* R7       = wsh + 149305344LL;      // 33,177,600 H_t
    _Float16* pct16    = wsh + 182482944LL;      // 6,255,360
    _Float16* pctinvT  = wsh + 188738304LL;      // 6,255,360
    _Float16* fwdTwT   = wsh + 194993664LL;      // 147,456
    _Float16* invTwT   = wsh + 195141120LL;      // 147,456
    _Float16* winner16 = wsh + 195288576LL;      // 131,072
    _Float16* wfc116   = wsh + 195419648LL;      // 262,144
    _Float16* wfc216   = wsh + 195681792LL;      // 262,144
    _Float16* wout16   = wsh + 195943936LL;      // 32,768

    // ---- setup ----
    hipMemsetAsync(Xc, 0, 17694720LL*2, stream);
    hipMemsetAsync(P,  0, 17793024LL*2, stream);
    tx_k<<<dim3(2025,8), 256, 0, stream>>>(x, X_t, Xc);
    build_tw16_k<<<576, 256, 0, stream>>>(fwdTwT, invTwT);
    cvt_pct_k<<<24435, 256, 0, stream>>>(pct, pct16);
    cvt_pctinvT_k<<<dim3(6,6,181), 256, 0, stream>>>(pctinv, pctinvT);
    build_wc_k<<<dim3(256,8,12), 256, 0, stream>>>(wspec, Wc);
    cast_k<<<512, 256, 0, stream>>>(winner, winner16, 131072);
    cast_k<<<1024, 256, 0, stream>>>(wfc1, wfc116, 262144);
    cast_k<<<1024, 256, 0, stream>>>(wfc2, wfc216, 262144);
    cast_k<<<128, 256, 0, stream>>>(wout, wout16, 32768);

    for (int layer = 0; layer < 2; layer++){
        _Float16 *XF = R5, *xfm = P, *spec = R5, *c2 = R6;
        _Float16 *c3 = P, *Z = R6, *XI = R5, *Yc = R6, *Y_t = R5, *H_t = R7;
        GemmP p; p.C2 = nullptr; p.D = nullptr; p.ldd = 0;

        // DFT: Xc [46080][384] x fwdTwT [362][384] -> XF [46080][362]
        p.A = Xc; p.Bt = fwdTwT; p.C = XF;
        p.aBS = 0; p.bBS = 0; p.cBS = 0;
        p.lda = 384; p.ldb = 384; p.ldc = 362;
        p.I = 46080; p.J = 362; p.K = 384;
        mfma_gemm<0,0,_Float16><<<dim3(3,360,1), 256, 0, stream>>>(p);

        // P1: XF -> xfm [m][2c+s][192]
        p1_k<<<dim3(6,1440,2), 256, 0, stream>>>(XF, xfm);

        // fwd Legendre (batch m): pct16[m][180 l][192] x xfm[m][512][192]
        //   -> spec [l][362 rows][512]: rows 0-180 = signed re-combined, 181-361 = dual
        p.A = pct16; p.Bt = xfm; p.C = spec; p.C2 = spec + 92672;
        p.aBS = 34560; p.bBS = 98304; p.cBS = 512;
        p.lda = 192; p.ldb = 192; p.ldc = 185344;
        p.I = 180; p.J = 512; p.K = 192;
        mfma_gemm<2,0,_Float16><<<dim3(4,2,181), 256, 0, stream>>>(p);
        p.C2 = nullptr;

        // dhconv (batch l): Wc[l][256][512] x spec[l] [362 rows][512] -> c2 [l][512 o2][181 m]
        p.A = Wc + (long long)layer*23592960LL; p.Bt = spec; p.C = c2;
        p.aBS = 131072; p.bBS = 185344; p.cBS = 92672;
        p.lda = 512; p.ldb = 512; p.ldc = 181;
        p.I = 256; p.J = 362; p.K = 512;
        mfma_gemm<3,0,_Float16><<<dim3(3,2,180), 256, 0, stream>>>(p);

        // permute: c2 -> c3 [m][o2][192(l)]
        plm_k<<<dim3(6,6,512), 256, 0, stream>>>(c2, c3);

        // inv Legendre (batch m): c3[m][512][192] x pctinvT[m][180 h][192] -> Z [m][o2][h]
        p.A = c3; p.Bt = pctinvT; p.C = Z;
        p.aBS = 98304; p.bBS = 34560; p.cBS = 92160;
        p.lda = 192; p.ldb = 192; p.ldc = 180;
        p.I = 512; p.J = 180; p.K = 192;
        mfma_gemm<0,0,_Float16><<<dim3(2,4,181), 256, 0, stream>>>(p);

        // P2: Z -> XI [(c,h)][384]
        zero_xi_k<<<5760, 256, 0, stream>>>(XI);
        p2_k<<<dim3(6,6,512), 256, 0, stream>>>(Z, XI);

        // iDFT: XI [46080][384] x invTwT [360][384] -> Yc [46080][360]
        p.A = XI; p.Bt = invTwT; p.C = Yc;
        p.aBS = 0; p.bBS = 0; p.cBS = 0;
        p.lda = 384; p.ldb = 384; p.ldc = 360;
        p.I = 46080; p.J = 360; p.K = 384;
        mfma_gemm<0,0,_Float16><<<dim3(3,360,1), 256, 0, stream>>>(p);

        // inner skip: Y_t[hw][256] = gelu(winner@X_t + Yc)
        p.A = winner16 + (long long)layer*65536; p.Bt = X_t; p.C = Y_t;
        p.D = Yc; p.ldd = 64800;
        p.lda = 256; p.ldb = 256; p.ldc = 256;
        p.I = 256; p.J = 64800; p.K = 256;
        mfma_gemm<1,5,_Float16><<<dim3(507,2,1), 256, 0, stream>>>(p);
        p.D = nullptr; p.ldd = 0;

        // fc1 + gelu -> H_t [hw][512]
        p.A = wfc116 + (long long)layer*131072; p.Bt = Y_t; p.C = H_t;
        p.lda = 256; p.ldb = 256; p.ldc = 512;
        p.I = 512; p.J = 64800; p.K = 256;
        mfma_gemm<1,1,_Float16><<<dim3(507,4,1), 256, 0, stream>>>(p);

        // fc2 + residual + gelu -> X_t ; layer 0 also dual-stores next Xc
        p.A = wfc216 + (long long)layer*131072; p.Bt = H_t; p.C = X_t;
        p.lda = 512; p.ldb = 512; p.ldc = 256;
        p.I = 256; p.J = 64800; p.K = 512;
        if (layer == 0){
            p.C2 = Xc;
            mfma_gemm<1,11,_Float16><<<dim3(507,2,1), 256, 0, stream>>>(p);
            p.C2 = nullptr;
        } else {
            mfma_gemm<1,3,_Float16><<<dim3(507,2,1), 256, 0, stream>>>(p);
        }
    }

    // final: wout16 [128][256] x X_t -> d_out f32 [128][64800]
    GemmP p; p.C2 = nullptr; p.D = nullptr; p.ldd = 0;
    p.A = wout16; p.Bt = X_t; p.C = outp;
    p.aBS = 0; p.bBS = 0; p.cBS = 0;
    p.lda = 256; p.ldb = 256; p.ldc = 64800;
    p.I = 128; p.J = 64800; p.K = 256;
    mfma_gemm<0,0,float><<<dim3(507,1,1), 256, 0, stream>>>(p);
}